// Round 10
// baseline (51.975 us; speedup 1.0000x reference)
//
#include <hip/hip_runtime.h>

typedef __attribute__((ext_vector_type(4))) float f32x4;
typedef __attribute__((ext_vector_type(8))) short bf16x8;

constexpr float EFF_DT = 0.01f;   // DT * DT_SCALE
constexpr float HH     = 0.005f;  // 0.5 * eff_dt ; mu = 0
constexpr float INV_DT = 100.0f;  // 1 / EFF_DT

__device__ inline short f2bf(float x){
    union{float f;unsigned u;}c; c.f=x;
    unsigned r=c.u+0x7FFFu+((c.u>>16)&1u);   // RNE
    return (short)(r>>16);
}
__device__ inline unsigned cvtpk(float lo,float hi){
    unsigned r; asm("v_cvt_pk_bf16_f32 %0, %1, %2":"=v"(r):"v"(lo),"v"(hi)); return r;
}
__device__ inline float ubflo(unsigned u){union{unsigned x;float f;}c;c.x=u<<16;return c.f;}
__device__ inline float ubfhi(unsigned u){union{unsigned x;float f;}c;c.x=u&0xffff0000u;return c.f;}

union VP4 { unsigned u[4]; bf16x8 h; };

// v10 (44.2us proven) + nsteps==8 full unroll (cross-half-step scheduling seams)
// + s_setprio(1) around the phase-A MFMA chain / t2 pack (free-running waves).
// Block = 256 threads (4 waves); each wave owns 16 batch rows; main loop barrier-free.
// Lane (g=lane>>4, c=lane&15) holds d = dt*16 + g*4 + j of batch row (R0+c) for all dt.
// Register regime: (256,2) -> 128 arch + 128 acc; VALU-active = vv(64)+fpk(32)+temps
// fits 128; uf[2][8] read-only -> AGPR; xacc fp32 in per-wave LDS; WF = -HH*W in LDS;
// v-update fused into phase-B MFMA C-operand (nv = mfma(wf, t2, vv + h*f)).
__global__ __launch_bounds__(256,2) void leapfrog_v11(
    const float* __restrict__ x_in, const float* __restrict__ v_in,
    const float* __restrict__ f_in, const float* __restrict__ Ug,
    const float* __restrict__ Wg, const int* __restrict__ steps_p,
    float* __restrict__ out)
{
    __shared__ __align__(16) char lds[81920];
    short* WF = (short*)lds;                       // 16KB: (-HH*W)^T A-frags

    const int tid=threadIdx.x, w=tid>>6, lane=tid&63, g=lane>>4, c=lane&15;
    const int R0 = blockIdx.x*64 + w*16;
    const int gb = (R0+c)*256 + g*4;
    const int BD = 32768*256;
    float* xw = (float*)(lds + 16384 + w*16384);   // per-wave xacc [16 dt][64 lane][4]

    // ---- persistent per-lane state ----
    f32x4 vv[16];               // fp32 carry (exact)
    unsigned fpk[16][2];        // bf16(h*f) packed
    bf16x8 uf[2][8];            // U^T A-frags, read-only -> AGPR

    // ---- v loads first (needed by first phase A) ----
    #pragma unroll
    for(int dt=0;dt<16;++dt) vv[dt] = *(const f32x4*)&v_in[gb+dt*16];

    // ---- build uf straight from global (L2-hot 32KB) ----
    #pragma unroll
    for(int rt=0;rt<2;++rt){
        #pragma unroll
        for(int cc=0;cc<8;++cc){
            bf16x8 e;
            #pragma unroll
            for(int j=0;j<8;++j){
                const int kk = ((j>>2)<<4) + g*4 + (j&3);    // kmap(g,j)
                e[j] = f2bf(Ug[(cc*32+kk)*32 + rt*16 + c]);  // U[d][r]
            }
            uf[rt][cc] = e;
        }
    }
    // ---- build WF (4 of 16 dt-tiles per wave) into LDS, -HH folded ----
    #pragma unroll
    for(int i=0;i<4;++i){
        const int t = w*4+i;
        bf16x8 e;
        #pragma unroll
        for(int j=0;j<8;++j){
            const int kk = ((j>>2)<<4) + g*4 + (j&3);
            e[j] = f2bf(-HH * Wg[kk*256 + t*16 + c]);        // -HH*W[r][d]
        }
        *(bf16x8*)&WF[t*512 + lane*8] = e;
    }
    // ---- f -> packed regs ; x -> per-wave LDS xacc (scaled by 1/dt) ----
    #pragma unroll
    for(int dt=0;dt<16;++dt){
        f32x4 ff = *(const f32x4*)&f_in[gb+dt*16];
        fpk[dt][0]=cvtpk(HH*ff[0],HH*ff[1]);
        fpk[dt][1]=cvtpk(HH*ff[2],HH*ff[3]);
    }
    #pragma unroll
    for(int dt=0;dt<16;++dt){
        f32x4 xx = *(const f32x4*)&x_in[gb+dt*16];
        f32x4 xs; xs[0]=INV_DT*xx[0]; xs[1]=INV_DT*xx[1];
        xs[2]=INV_DT*xx[2]; xs[3]=INV_DT*xx[3];
        *(f32x4*)&xw[dt*256 + lane*4] = xs;
    }
    __syncthreads();   // WF visible to all waves (only barrier)

    const int nsteps = *steps_p;
    const f32x4 zero = {0.f,0.f,0.f,0.f};

    // ACCX: half-0 (accumulate x). STX: store final x (last half-0). STV: store final v.
#define PHASE_AB(ACCX, STX, STV) do { \
    f32x4 a00=zero,a01=zero,a10=zero,a11=zero; \
    __builtin_amdgcn_s_setprio(1); \
    _Pragma("unroll") \
    for(int cc=0;cc<8;++cc){ \
        VP4 vp; \
        vp.u[0]=cvtpk(vv[2*cc][0],  vv[2*cc][1]); \
        vp.u[1]=cvtpk(vv[2*cc][2],  vv[2*cc][3]); \
        vp.u[2]=cvtpk(vv[2*cc+1][0],vv[2*cc+1][1]); \
        vp.u[3]=cvtpk(vv[2*cc+1][2],vv[2*cc+1][3]); \
        if(cc&1){ a01=__builtin_amdgcn_mfma_f32_16x16x32_bf16(uf[0][cc],vp.h,a01,0,0,0); \
                  a11=__builtin_amdgcn_mfma_f32_16x16x32_bf16(uf[1][cc],vp.h,a11,0,0,0); } \
        else    { a00=__builtin_amdgcn_mfma_f32_16x16x32_bf16(uf[0][cc],vp.h,a00,0,0,0); \
                  a10=__builtin_amdgcn_mfma_f32_16x16x32_bf16(uf[1][cc],vp.h,a10,0,0,0); } \
    } \
    { \
        float t00=a00[0]+a01[0], t01=a00[1]+a01[1], t02=a00[2]+a01[2], t03=a00[3]+a01[3]; \
        float t10=a10[0]+a11[0], t11=a10[1]+a11[1], t12=a10[2]+a11[2], t13=a10[3]+a11[3]; \
        VP4 t2; \
        t2.u[0]=cvtpk(t00*t00, t01*t01); \
        t2.u[1]=cvtpk(t02*t02, t03*t03); \
        t2.u[2]=cvtpk(t10*t10, t11*t11); \
        t2.u[3]=cvtpk(t12*t12, t13*t13); \
        __builtin_amdgcn_s_setprio(0); \
        _Pragma("unroll") \
        for(int dt=0;dt<16;++dt){ \
            bf16x8 wf=*(bf16x8*)&WF[dt*512 + lane*8]; \
            const unsigned f0=fpk[dt][0], f1=fpk[dt][1]; \
            f32x4 cin; \
            cin[0]=vv[dt][0]+ubflo(f0); \
            cin[1]=vv[dt][1]+ubfhi(f0); \
            cin[2]=vv[dt][2]+ubflo(f1); \
            cin[3]=vv[dt][3]+ubfhi(f1); \
            f32x4 nv=__builtin_amdgcn_mfma_f32_16x16x32_bf16(wf,t2.h,cin,0,0,0); \
            vv[dt]=nv; \
            if(ACCX){ \
                f32x4* xp=(f32x4*)&xw[dt*256 + lane*4]; \
                f32x4 xv=*xp; \
                xv[0]+=nv[0]; xv[1]+=nv[1]; xv[2]+=nv[2]; xv[3]+=nv[3]; \
                if(STX){ \
                    f32x4 xo; \
                    xo[0]=EFF_DT*xv[0]; xo[1]=EFF_DT*xv[1]; \
                    xo[2]=EFF_DT*xv[2]; xo[3]=EFF_DT*xv[3]; \
                    *(f32x4*)&out[gb+dt*16] = xo; \
                }else{ \
                    *xp = xv; \
                } \
            } \
            if(STV){ \
                *(f32x4*)&out[BD+gb+dt*16] = nv; \
            } \
        } \
    } \
} while(0)

    if(nsteps == 8){
        // straight-line: exposes the 7 backedge seams to the scheduler
        #pragma unroll
        for(int s=0;s<7;++s){
            PHASE_AB(1,0,0);   // half 0: v_half ; xacc += v_half
            PHASE_AB(0,0,0);   // half 1: v update
        }
        PHASE_AB(1,1,0);       // last half 0: x final -> store x (write drains early)
        PHASE_AB(0,0,1);       // last half 1: v final -> store v
    }else{
        for(int s=0;s<nsteps-1;++s){
            PHASE_AB(1,0,0);
            PHASE_AB(0,0,0);
        }
        PHASE_AB(1,1,0);
        PHASE_AB(0,0,1);
    }
#undef PHASE_AB
}

extern "C" void kernel_launch(void* const* d_in, const int* in_sizes, int n_in,
                              void* d_out, int out_size, void* d_ws, size_t ws_size,
                              hipStream_t stream) {
    (void)in_sizes; (void)n_in; (void)d_ws; (void)ws_size; (void)out_size;
    const float* x_in = (const float*)d_in[0];
    const float* v_in = (const float*)d_in[1];
    const float* f_in = (const float*)d_in[2];
    const float* Ug   = (const float*)d_in[3];
    const float* Wg   = (const float*)d_in[4];
    const int*   st   = (const int*)d_in[5];
    float* out = (float*)d_out;

    dim3 grid(32768/64), block(256);
    hipLaunchKernelGGL(leapfrog_v11, grid, block, 0, stream,
                       x_in, v_in, f_in, Ug, Wg, st, out);
}

// Round 12
// 43.438 us; speedup vs baseline: 1.1966x; 1.1966x over previous
//
#include <hip/hip_runtime.h>

typedef __attribute__((ext_vector_type(4))) float f32x4;
typedef __attribute__((ext_vector_type(8))) short bf16x8;

constexpr float EFF_DT = 0.01f;   // DT * DT_SCALE
constexpr float HH     = 0.005f;  // 0.5 * eff_dt ; mu = 0
constexpr float INV_DT = 100.0f;  // 1 / EFF_DT

__device__ inline short f2bf(float x){
    union{float f;unsigned u;}c; c.f=x;
    unsigned r=c.u+0x7FFFu+((c.u>>16)&1u);   // RNE
    return (short)(r>>16);
}
__device__ inline unsigned cvtpk(float lo,float hi){
    unsigned r; asm("v_cvt_pk_bf16_f32 %0, %1, %2":"=v"(r):"v"(lo),"v"(hi)); return r;
}
__device__ inline float ubflo(unsigned u){union{unsigned x;float f;}c;c.x=u<<16;return c.f;}
__device__ inline float ubfhi(unsigned u){union{unsigned x;float f;}c;c.x=u&0xffff0000u;return c.f;}

union VP4 { unsigned u[4]; bf16x8 h; };

// EXACT v10 structure (proven 44.2us, absmax 0.03125) + s_setprio around the
// phase-A critical chain (regalloc-neutral: SALU hint, no operands).
// PINNED register configuration (r5/r6/r8/v11/v12 lessons — do not deviate):
//   __launch_bounds__(256,2): 128 arch VGPR + 128 acc.
//   vv(64)+fpk(32)+temps in arch VGPRs; uf[2][8] read-only -> AGPR (64);
//   WF in LDS (NOT registers — v12's wfr-in-AGPR broke numerics);
//   xacc fp32 in per-wave LDS (NOT registers — r5 spilled);
//   s-loop ROLLED (v11's unroll spilled 27MB).
// Block = 256 threads (4 waves); each wave owns 16 batch rows; loop barrier-free.
// Lane (g=lane>>4, c=lane&15) holds d = dt*16+g*4+j of batch row (R0+c) for all dt.
// v-update fused into phase-B MFMA C-operand (nv = mfma(WF=-HH*W, t2, vv+h*f)).
__global__ __launch_bounds__(256,2) void leapfrog_v13(
    const float* __restrict__ x_in, const float* __restrict__ v_in,
    const float* __restrict__ f_in, const float* __restrict__ Ug,
    const float* __restrict__ Wg, const int* __restrict__ steps_p,
    float* __restrict__ out)
{
    __shared__ __align__(16) char lds[81920];
    short* WF = (short*)lds;                       // 16KB: (-HH*W)^T A-frags

    const int tid=threadIdx.x, w=tid>>6, lane=tid&63, g=lane>>4, c=lane&15;
    const int R0 = blockIdx.x*64 + w*16;
    const int gb = (R0+c)*256 + g*4;
    const int BD = 32768*256;
    float* xw = (float*)(lds + 16384 + w*16384);   // per-wave xacc [16 dt][64 lane][4]

    // ---- persistent per-lane state ----
    f32x4 vv[16];               // fp32 carry (exact)
    unsigned fpk[16][2];        // bf16(h*f) packed
    bf16x8 uf[2][8];            // U^T A-frags, read-only -> AGPR

    // ---- v loads first (needed by first phase A) ----
    #pragma unroll
    for(int dt=0;dt<16;++dt) vv[dt] = *(const f32x4*)&v_in[gb+dt*16];

    // ---- build uf straight from global (L2-hot 32KB) ----
    #pragma unroll
    for(int rt=0;rt<2;++rt){
        #pragma unroll
        for(int cc=0;cc<8;++cc){
            bf16x8 e;
            #pragma unroll
            for(int j=0;j<8;++j){
                const int kk = ((j>>2)<<4) + g*4 + (j&3);    // kmap(g,j)
                e[j] = f2bf(Ug[(cc*32+kk)*32 + rt*16 + c]);  // U[d][r]
            }
            uf[rt][cc] = e;
        }
    }
    // ---- build WF (4 of 16 dt-tiles per wave) into LDS, -HH folded ----
    #pragma unroll
    for(int i=0;i<4;++i){
        const int t = w*4+i;
        bf16x8 e;
        #pragma unroll
        for(int j=0;j<8;++j){
            const int kk = ((j>>2)<<4) + g*4 + (j&3);
            e[j] = f2bf(-HH * Wg[kk*256 + t*16 + c]);        // -HH*W[r][d]
        }
        *(bf16x8*)&WF[t*512 + lane*8] = e;
    }
    // ---- f -> packed regs ; x -> per-wave LDS xacc (scaled by 1/dt) ----
    #pragma unroll
    for(int dt=0;dt<16;++dt){
        f32x4 ff = *(const f32x4*)&f_in[gb+dt*16];
        fpk[dt][0]=cvtpk(HH*ff[0],HH*ff[1]);
        fpk[dt][1]=cvtpk(HH*ff[2],HH*ff[3]);
    }
    #pragma unroll
    for(int dt=0;dt<16;++dt){
        f32x4 xx = *(const f32x4*)&x_in[gb+dt*16];
        f32x4 xs; xs[0]=INV_DT*xx[0]; xs[1]=INV_DT*xx[1];
        xs[2]=INV_DT*xx[2]; xs[3]=INV_DT*xx[3];
        *(f32x4*)&xw[dt*256 + lane*4] = xs;
    }
    __syncthreads();   // WF visible to all waves (only barrier)

    const int nsteps = *steps_p;
    const f32x4 zero = {0.f,0.f,0.f,0.f};

    // ACCX: half-0 (accumulate x). STX: store final x (last half-0). STV: store final v.
#define PHASE_AB(ACCX, STX, STV) do { \
    f32x4 a00=zero,a01=zero,a10=zero,a11=zero; \
    __builtin_amdgcn_s_setprio(1); \
    _Pragma("unroll") \
    for(int cc=0;cc<8;++cc){ \
        VP4 vp; \
        vp.u[0]=cvtpk(vv[2*cc][0],  vv[2*cc][1]); \
        vp.u[1]=cvtpk(vv[2*cc][2],  vv[2*cc][3]); \
        vp.u[2]=cvtpk(vv[2*cc+1][0],vv[2*cc+1][1]); \
        vp.u[3]=cvtpk(vv[2*cc+1][2],vv[2*cc+1][3]); \
        if(cc&1){ a01=__builtin_amdgcn_mfma_f32_16x16x32_bf16(uf[0][cc],vp.h,a01,0,0,0); \
                  a11=__builtin_amdgcn_mfma_f32_16x16x32_bf16(uf[1][cc],vp.h,a11,0,0,0); } \
        else    { a00=__builtin_amdgcn_mfma_f32_16x16x32_bf16(uf[0][cc],vp.h,a00,0,0,0); \
                  a10=__builtin_amdgcn_mfma_f32_16x16x32_bf16(uf[1][cc],vp.h,a10,0,0,0); } \
    } \
    { \
        float t00=a00[0]+a01[0], t01=a00[1]+a01[1], t02=a00[2]+a01[2], t03=a00[3]+a01[3]; \
        float t10=a10[0]+a11[0], t11=a10[1]+a11[1], t12=a10[2]+a11[2], t13=a10[3]+a11[3]; \
        VP4 t2; \
        t2.u[0]=cvtpk(t00*t00, t01*t01); \
        t2.u[1]=cvtpk(t02*t02, t03*t03); \
        t2.u[2]=cvtpk(t10*t10, t11*t11); \
        t2.u[3]=cvtpk(t12*t12, t13*t13); \
        __builtin_amdgcn_s_setprio(0); \
        _Pragma("unroll") \
        for(int dt=0;dt<16;++dt){ \
            bf16x8 wf=*(bf16x8*)&WF[dt*512 + lane*8]; \
            const unsigned f0=fpk[dt][0], f1=fpk[dt][1]; \
            f32x4 cin; \
            cin[0]=vv[dt][0]+ubflo(f0); \
            cin[1]=vv[dt][1]+ubfhi(f0); \
            cin[2]=vv[dt][2]+ubflo(f1); \
            cin[3]=vv[dt][3]+ubfhi(f1); \
            f32x4 nv=__builtin_amdgcn_mfma_f32_16x16x32_bf16(wf,t2.h,cin,0,0,0); \
            vv[dt]=nv; \
            if(ACCX){ \
                f32x4* xp=(f32x4*)&xw[dt*256 + lane*4]; \
                f32x4 xv=*xp; \
                xv[0]+=nv[0]; xv[1]+=nv[1]; xv[2]+=nv[2]; xv[3]+=nv[3]; \
                if(STX){ \
                    f32x4 xo; \
                    xo[0]=EFF_DT*xv[0]; xo[1]=EFF_DT*xv[1]; \
                    xo[2]=EFF_DT*xv[2]; xo[3]=EFF_DT*xv[3]; \
                    *(f32x4*)&out[gb+dt*16] = xo; \
                }else{ \
                    *xp = xv; \
                } \
            } \
            if(STV){ \
                *(f32x4*)&out[BD+gb+dt*16] = nv; \
            } \
        } \
    } \
} while(0)

    for(int s=0;s<nsteps-1;++s){
        PHASE_AB(1,0,0);   // half 0: v_half ; xacc += v_half
        PHASE_AB(0,0,0);   // half 1: v update
    }
    PHASE_AB(1,1,0);       // last half 0: x final -> store x (write drains early)
    PHASE_AB(0,0,1);       // last half 1: v final -> store v
#undef PHASE_AB
}

extern "C" void kernel_launch(void* const* d_in, const int* in_sizes, int n_in,
                              void* d_out, int out_size, void* d_ws, size_t ws_size,
                              hipStream_t stream) {
    (void)in_sizes; (void)n_in; (void)d_ws; (void)ws_size; (void)out_size;
    const float* x_in = (const float*)d_in[0];
    const float* v_in = (const float*)d_in[1];
    const float* f_in = (const float*)d_in[2];
    const float* Ug   = (const float*)d_in[3];
    const float* Wg   = (const float*)d_in[4];
    const int*   st   = (const int*)d_in[5];
    float* out = (float*)d_out;

    dim3 grid(32768/64), block(256);
    hipLaunchKernelGGL(leapfrog_v13, grid, block, 0, stream,
                       x_in, v_in, f_in, Ug, Wg, st, out);
}